// Round 1
// baseline (199.498 us; speedup 1.0000x reference)
//
#include <hip/hip_runtime.h>

typedef __bf16 bf16x8 __attribute__((ext_vector_type(8)));
typedef float floatx4 __attribute__((ext_vector_type(4)));

#define XS 136  // LDS row stride in bf16 elements (128 + 8 pad -> 272B, 2-way bank aliasing = free)

__device__ __forceinline__ unsigned short f32_bf16(float f) {
    union { float f; unsigned int u; } c; c.f = f;
    return (unsigned short)((c.u + 0x7fffu + ((c.u >> 16) & 1u)) >> 16);  // RNE, inputs are finite
}

__global__ __launch_bounds__(256) void prep_w1(const float* __restrict__ w1,
                                               unsigned short* __restrict__ wbf) {
    int i = blockIdx.x * 256 + threadIdx.x;   // 131072 = 512 * 256
    wbf[i] = f32_bf16(w1[i]);
}

// One workgroup = 128 rows (samples) x all 1024 columns (2 experts x 512 hidden).
// wave w: m-half = w&1 (rows mh*64..mh*64+63), expert/n-half = w>>1.
__global__ __launch_bounds__(256) void moe_fused(
    const float* __restrict__ x,
    const unsigned short* __restrict__ wbf,   // [1024][128] bf16 (e*512+h rows, d cols)
    const float* __restrict__ b1,             // [2][512]
    const float* __restrict__ w2,             // [2][2][512]
    const float* __restrict__ b2,             // [2][2]
    const float* __restrict__ protos,         // [2][128]
    float* __restrict__ out)                  // [B][2]
{
    __shared__ unsigned short xs[128 * XS];   // bf16 x tile, row-major padded
    __shared__ float proto_s[2 * 128];
    __shared__ float b1_s[2 * 512];
    __shared__ float w2_s[4 * 512];
    __shared__ float out_s[128 * 4];          // [row][e][o]
    __shared__ int   t_s[128];

    const int tid  = threadIdx.x;
    const int lane = tid & 63;
    const int wave = tid >> 6;
    const int quad = lane >> 4;
    const int l15  = lane & 15;
    const int mh   = wave & 1;
    const int nh   = wave >> 1;               // expert index for this wave
    const long rowbase = (long)blockIdx.x * 128;

    // ---- stage small tables ----
    for (int i = tid; i < 256;  i += 256) proto_s[i] = protos[i];
    for (int i = tid; i < 1024; i += 256) b1_s[i]    = b1[i];
    for (int i = tid; i < 2048; i += 256) w2_s[i]    = w2[i];

    // ---- stage x tile: coalesced float4 global reads, convert to bf16 LDS ----
    for (int i = tid; i < 128 * 32; i += 256) {
        int r  = i >> 5;
        int c4 = (i & 31) * 4;
        float4 v = *(const float4*)(x + (rowbase + r) * 128 + c4);
        unsigned short* d = &xs[r * XS + c4];
        d[0] = f32_bf16(v.x); d[1] = f32_bf16(v.y);
        d[2] = f32_bf16(v.z); d[3] = f32_bf16(v.w);
    }
    __syncthreads();

    // ---- routing in fp64 (exact vs reference; ties -> expert 0) ----
    {
        const int sub = tid & 15;     // 16 threads per row: 2 experts x 8 strided chains
        const int e   = sub >> 3;
        const int j   = sub & 7;
        const float* pr = proto_s + e * 128;
        for (int rb = 0; rb < 128; rb += 16) {
            int r = rb + (tid >> 4);
            const float* xr = x + (rowbase + r) * 128;
            double acc = 0.0;
            #pragma unroll
            for (int k = 0; k < 16; ++k) {
                int c = j + 8 * k;
                double d = (double)xr[c] - (double)pr[c];
                acc = fma(d, d, acc);
            }
            acc += __shfl_xor(acc, 1);
            acc += __shfl_xor(acc, 2);
            acc += __shfl_xor(acc, 4);        // all 8 j-lanes now hold this expert's d2
            double other = __shfl_xor(acc, 8); // the other expert's d2
            if (sub == 0) t_s[r] = (other < acc) ? 1 : 0;
        }
    }

    // ---- preload A fragments: 4 m-tiles x 4 k-steps, kept in registers ----
    // A-operand layout: A[m = lane&15][k = quad*8 + j]
    bf16x8 afrag[4][4];
    #pragma unroll
    for (int mt = 0; mt < 4; ++mt) {
        int r = mh * 64 + mt * 16 + l15;
        #pragma unroll
        for (int ks = 0; ks < 4; ++ks)
            afrag[mt][ks] = *(const bf16x8*)&xs[r * XS + ks * 32 + quad * 8];
    }

    float outp[4][4][2] = {};   // [m-tile][reg(row)][o] partial layer-2 accum

    // ---- main loop: 32 n-tiles of 16 columns within this wave's expert ----
    // B-operand layout: B[k = quad*8 + j][n = lane&15]; wbf row n is k-contiguous.
    const unsigned short* wb_base = wbf + (long)(nh * 512 + l15) * 128 + quad * 8;
    for (int nt = 0; nt < 32; ++nt) {
        const unsigned short* wb = wb_base + nt * 16 * 128;
        bf16x8 bf0 = *(const bf16x8*)(wb);
        bf16x8 bf1 = *(const bf16x8*)(wb + 32);
        bf16x8 bf2 = *(const bf16x8*)(wb + 64);
        bf16x8 bf3 = *(const bf16x8*)(wb + 96);
        int hcol = nt * 16 + l15;
        float bb  = b1_s[nh * 512 + hcol];
        float w2a = w2_s[(nh * 2 + 0) * 512 + hcol];
        float w2b = w2_s[(nh * 2 + 1) * 512 + hcol];
        #pragma unroll
        for (int mt = 0; mt < 4; ++mt) {
            floatx4 c = {0.f, 0.f, 0.f, 0.f};
            c = __builtin_amdgcn_mfma_f32_16x16x32_bf16(afrag[mt][0], bf0, c, 0, 0, 0);
            c = __builtin_amdgcn_mfma_f32_16x16x32_bf16(afrag[mt][1], bf1, c, 0, 0, 0);
            c = __builtin_amdgcn_mfma_f32_16x16x32_bf16(afrag[mt][2], bf2, c, 0, 0, 0);
            c = __builtin_amdgcn_mfma_f32_16x16x32_bf16(afrag[mt][3], bf3, c, 0, 0, 0);
            // fused epilogue: bias + relu + layer2 partial
            #pragma unroll
            for (int rg = 0; rg < 4; ++rg) {
                float h = fmaxf(c[rg] + bb, 0.0f);
                outp[mt][rg][0] += h * w2a;
                outp[mt][rg][1] += h * w2b;
            }
        }
    }

    // ---- reduce layer-2 partials across the 16 column-lanes ----
    #pragma unroll
    for (int mt = 0; mt < 4; ++mt)
        #pragma unroll
        for (int rg = 0; rg < 4; ++rg)
            #pragma unroll
            for (int o = 0; o < 2; ++o) {
                float v = outp[mt][rg][o];
                v += __shfl_xor(v, 1);
                v += __shfl_xor(v, 2);
                v += __shfl_xor(v, 4);
                v += __shfl_xor(v, 8);
                outp[mt][rg][o] = v;
            }
    if (l15 == 0) {
        #pragma unroll
        for (int mt = 0; mt < 4; ++mt)
            #pragma unroll
            for (int rg = 0; rg < 4; ++rg) {
                int r = mh * 64 + mt * 16 + quad * 4 + rg;  // C/D: row = quad*4 + reg
                out_s[r * 4 + nh * 2 + 0] = outp[mt][rg][0];
                out_s[r * 4 + nh * 2 + 1] = outp[mt][rg][1];
            }
    }
    __syncthreads();

    // ---- select expert per row, add b2, coalesced store ----
    {
        int r  = tid >> 1;
        int o  = tid & 1;
        int te = t_s[r];
        out[(rowbase + r) * 2 + o] = out_s[r * 4 + te * 2 + o] + b2[te * 2 + o];
    }
}

extern "C" void kernel_launch(void* const* d_in, const int* in_sizes, int n_in,
                              void* d_out, int out_size, void* d_ws, size_t ws_size,
                              hipStream_t stream) {
    const float* x      = (const float*)d_in[0];
    const float* w1     = (const float*)d_in[1];
    const float* b1     = (const float*)d_in[2];
    const float* w2     = (const float*)d_in[3];
    const float* b2     = (const float*)d_in[4];
    const float* protos = (const float*)d_in[5];
    float* out = (float*)d_out;
    unsigned short* wbf = (unsigned short*)d_ws;   // 256 KiB bf16 weights

    prep_w1<<<dim3(512), dim3(256), 0, stream>>>(w1, wbf);
    moe_fused<<<dim3(1024), dim3(256), 0, stream>>>(x, wbf, b1, w2, b2, protos, out);
}

// Round 2
// 158.857 us; speedup vs baseline: 1.2558x; 1.2558x over previous
//
#include <hip/hip_runtime.h>

typedef __bf16 bf16x8 __attribute__((ext_vector_type(8)));
typedef float floatx4 __attribute__((ext_vector_type(4)));

#define XS 136  // LDS row stride in bf16 elements (272 B -> 2-way bank aliasing = free)

__device__ __forceinline__ unsigned short f32_bf16(float f) {
    union { float f; unsigned int u; } c; c.f = f;
    return (unsigned short)((c.u + 0x7fffu + ((c.u >> 16) & 1u)) >> 16);  // RNE, finite inputs
}

// Re-layout w1 into MFMA B-fragment order so the main loop's weight loads are
// fully coalesced: frag (e, nt, ks) holds B[k=quad*8+j][n=l15], 8 shorts/lane.
// wbf[ ((e*32+nt)*4+ks)*512 + lane*8 + j ] = bf16( w1[e][nt*16+l15][ks*32+quad*8+j] )
__global__ __launch_bounds__(256) void prep_w1_frag(const float* __restrict__ w1,
                                                    unsigned short* __restrict__ wbf) {
    int g    = blockIdx.x * 256 + threadIdx.x;   // 64 blocks -> 16384 threads
    int lane = g & 63;
    int frag = g >> 6;                            // 0..255
    int ks   = frag & 3;
    int nt   = (frag >> 2) & 31;
    int e    = frag >> 7;
    int l15  = lane & 15;
    int quad = lane >> 4;
    const float* src = w1 + ((e * 512 + nt * 16 + l15) * 128 + ks * 32 + quad * 8);
    unsigned short* dst = wbf + (long)g * 8;      // 16 B/lane, contiguous per wave
    #pragma unroll
    for (int j = 0; j < 8; ++j) dst[j] = f32_bf16(src[j]);
}

// One workgroup = 128 rows x all 1024 columns (2 experts x 512 hidden).
// wave w: m-half = w&1 (rows mh*64..mh*64+63), expert = w>>1.
__global__ __launch_bounds__(256, 4) void moe_fused(
    const float* __restrict__ x,
    const unsigned short* __restrict__ wbf,   // fragment-ordered bf16 w1
    const float* __restrict__ b1,             // [2][512]
    const float* __restrict__ w2,             // [2][2][512]
    const float* __restrict__ b2,             // [2][2]
    const float* __restrict__ protos,         // [2][128]
    float* __restrict__ out)                  // [B][2]
{
    __shared__ unsigned short xs[128 * XS];   // 34816 B
    __shared__ float out_s[128 * 4];          // [row][e][o]  2048 B
    __shared__ int   t_s[128];                // 512 B        -> total 37376 B => 4 blocks/CU

    const int tid  = threadIdx.x;
    const int lane = tid & 63;
    const int wave = tid >> 6;
    const int quad = lane >> 4;
    const int l15  = lane & 15;
    const int mh   = wave & 1;
    const int nh   = wave >> 1;               // expert index for this wave
    const long rowbase = (long)blockIdx.x * 128;

    // ---- stage x tile: coalesced float4 global reads -> bf16 LDS (8 B writes) ----
    for (int i = tid; i < 128 * 32; i += 256) {
        int r  = i >> 5;
        int c4 = (i & 31) * 4;
        float4 v = *(const float4*)(x + (rowbase + r) * 128 + c4);
        ushort4 p;
        p.x = f32_bf16(v.x); p.y = f32_bf16(v.y);
        p.z = f32_bf16(v.z); p.w = f32_bf16(v.w);
        *(ushort4*)&xs[r * XS + c4] = p;
    }
    __syncthreads();

    // ---- routing in fp64 (exact vs reference; ties -> expert 0) ----
    {
        const int sub = tid & 15;     // 16 threads/row: 2 experts x 8 strided chains
        const int e   = sub >> 3;
        const int j   = sub & 7;
        const float* pr = protos + e * 128;
        for (int rb = 0; rb < 128; rb += 16) {
            int r = rb + (tid >> 4);
            const float* xr = x + (rowbase + r) * 128;
            double acc = 0.0;
            #pragma unroll
            for (int k = 0; k < 16; ++k) {
                int c = j + 8 * k;
                double d = (double)xr[c] - (double)pr[c];
                acc = fma(d, d, acc);
            }
            acc += __shfl_xor(acc, 1);
            acc += __shfl_xor(acc, 2);
            acc += __shfl_xor(acc, 4);         // all 8 j-lanes hold this expert's d2
            double other = __shfl_xor(acc, 8); // the other expert's d2
            if (sub == 0) t_s[r] = (other < acc) ? 1 : 0;
        }
    }

    // ---- preload A fragments: 4 m-tiles x 4 k-steps, kept resident ----
    // A-operand layout: A[m = lane&15][k = quad*8 + j]
    bf16x8 afrag[4][4];
    #pragma unroll
    for (int mt = 0; mt < 4; ++mt) {
        int r = mh * 64 + mt * 16 + l15;
        #pragma unroll
        for (int ks = 0; ks < 4; ++ks)
            afrag[mt][ks] = *(const bf16x8*)&xs[r * XS + ks * 32 + quad * 8];
    }

    float outp[4][4][2] = {};   // [m-tile][reg(row)][o] layer-2 partials

    // ---- main loop: 32 n-tiles of 16 hidden cols within this wave's expert ----
    const bf16x8* wb8 = (const bf16x8*)wbf + (long)(nh * 32) * 4 * 64 + lane;
    for (int nt = 0; nt < 32; ++nt) {
        const bf16x8* wp = wb8 + nt * 4 * 64;
        bf16x8 bf0 = wp[0];
        bf16x8 bf1 = wp[64];
        bf16x8 bf2 = wp[128];
        bf16x8 bf3 = wp[192];
        int hcol  = nt * 16 + l15;
        float bb  = b1[nh * 512 + hcol];
        float w2a = w2[(nh * 2 + 0) * 512 + hcol];
        float w2b = w2[(nh * 2 + 1) * 512 + hcol];
        #pragma unroll
        for (int mt = 0; mt < 4; ++mt) {
            floatx4 c = {bb, bb, bb, bb};   // bias folded into accumulator init
            c = __builtin_amdgcn_mfma_f32_16x16x32_bf16(afrag[mt][0], bf0, c, 0, 0, 0);
            c = __builtin_amdgcn_mfma_f32_16x16x32_bf16(afrag[mt][1], bf1, c, 0, 0, 0);
            c = __builtin_amdgcn_mfma_f32_16x16x32_bf16(afrag[mt][2], bf2, c, 0, 0, 0);
            c = __builtin_amdgcn_mfma_f32_16x16x32_bf16(afrag[mt][3], bf3, c, 0, 0, 0);
            #pragma unroll
            for (int rg = 0; rg < 4; ++rg) {
                float h = fmaxf(c[rg], 0.0f);
                outp[mt][rg][0] = fmaf(h, w2a, outp[mt][rg][0]);
                outp[mt][rg][1] = fmaf(h, w2b, outp[mt][rg][1]);
            }
        }
    }

    // ---- reduce layer-2 partials across the 16 column-lanes ----
    #pragma unroll
    for (int mt = 0; mt < 4; ++mt)
        #pragma unroll
        for (int rg = 0; rg < 4; ++rg)
            #pragma unroll
            for (int o = 0; o < 2; ++o) {
                float v = outp[mt][rg][o];
                v += __shfl_xor(v, 1);
                v += __shfl_xor(v, 2);
                v += __shfl_xor(v, 4);
                v += __shfl_xor(v, 8);
                outp[mt][rg][o] = v;
            }
    if (l15 == 0) {
        #pragma unroll
        for (int mt = 0; mt < 4; ++mt)
            #pragma unroll
            for (int rg = 0; rg < 4; ++rg) {
                int r = mh * 64 + mt * 16 + quad * 4 + rg;  // C/D: row = quad*4 + reg
                out_s[r * 4 + nh * 2 + 0] = outp[mt][rg][0];
                out_s[r * 4 + nh * 2 + 1] = outp[mt][rg][1];
            }
    }
    __syncthreads();

    // ---- select expert per row, add b2, coalesced store ----
    {
        int r  = tid >> 1;
        int o  = tid & 1;
        int te = t_s[r];
        out[(rowbase + r) * 2 + o] = out_s[r * 4 + te * 2 + o] + b2[te * 2 + o];
    }
}

extern "C" void kernel_launch(void* const* d_in, const int* in_sizes, int n_in,
                              void* d_out, int out_size, void* d_ws, size_t ws_size,
                              hipStream_t stream) {
    const float* x      = (const float*)d_in[0];
    const float* w1     = (const float*)d_in[1];
    const float* b1     = (const float*)d_in[2];
    const float* w2     = (const float*)d_in[3];
    const float* b2     = (const float*)d_in[4];
    const float* protos = (const float*)d_in[5];
    float* out = (float*)d_out;
    unsigned short* wbf = (unsigned short*)d_ws;   // 256 KiB bf16 fragment-ordered w1

    prep_w1_frag<<<dim3(64), dim3(256), 0, stream>>>(w1, wbf);
    moe_fused<<<dim3(1024), dim3(256), 0, stream>>>(x, wbf, b1, w2, b2, protos, out);
}